// Round 7
// baseline (100.900 us; speedup 1.0000x reference)
//
#include <hip/hip_runtime.h>
#include <math.h>

#define BATCH 4096
#define DIM 256
#define FPC 8
#define NPAIR 14336   // 512 blocks * C(8,2)
#define SHIFT 22.0f

typedef __bf16 bf16x8 __attribute__((ext_vector_type(8)));
typedef float  f32x4  __attribute__((ext_vector_type(4)));

// fp32 -> bf16 round-to-nearest-even (inputs are finite normals; no NaN path)
__device__ __forceinline__ unsigned short f2bf(float f) {
    unsigned int u = __float_as_uint(f);
    u += 0x7FFFu + ((u >> 16) & 1u);
    return (unsigned short)(u >> 16);
}

// ---------------------------------------------------------------------------
// ws layout: [0,4096) f32 sq ; [4096,8192) f32 S ; then 4096*256 bf16 (2 MB)
// ---------------------------------------------------------------------------

__global__ __launch_bounds__(256) void prep_kernel(const float* __restrict__ x,
                                                   float* __restrict__ sq,
                                                   float* __restrict__ S,
                                                   unsigned short* __restrict__ xb,
                                                   float* __restrict__ out) {
    int t = blockIdx.x * 256 + threadIdx.x;
    int row = t >> 6;
    int lane = t & 63;
    float4 v = ((const float4*)(x + row * DIM))[lane];
    ushort4 b;
    b.x = f2bf(v.x); b.y = f2bf(v.y); b.z = f2bf(v.z); b.w = f2bf(v.w);
    ((ushort4*)(xb + row * DIM))[lane] = b;
    float s = v.x * v.x + v.y * v.y + v.z * v.z + v.w * v.w;
#pragma unroll
    for (int off = 32; off > 0; off >>= 1) s += __shfl_xor(s, off);
    if (lane == 0) { sq[row] = s; S[row] = 0.f; }
    if (t == 0) out[0] = 0.f;
}

// Upper-triangular 128x128 tile of dist = sqrt(sq_r - 2*X@X^T + sq_c).
// NO LDS: each wave loads its MFMA fragments directly from global (L2-resident
// xb). Fragment load for (i,kk): lane(quad,lcol) reads 8 contiguous bf16 at
// row (base+i*16+lcol), k-offset kk*32+quad*8 -> 16 rows x 64B-contiguous
// segments per instruction (line-granular). No barriers; the 8 kk groups are
// independent so the compiler pipelines loads across MFMAs with fine vmcnt.
__global__ __launch_bounds__(256) void dist_expsum_mfma(const unsigned short* __restrict__ xb,
                                                        const float* __restrict__ sq,
                                                        float* __restrict__ S) {
    // triangular decode: tile (bi, bj) with bi <= bj
    int t = blockIdx.x, bi = 0;
    while (t >= 32 - bi) { t -= 32 - bi; bi++; }
    const int bj = bi + t;
    const int row0 = bi * 128;
    const int col0 = bj * 128;
    const bool diagblk = (bi == bj);

    const int tid  = threadIdx.x;
    const int w    = tid >> 6;      // wave 0..3
    const int lane = tid & 63;
    const int wr   = w >> 1;        // wave row 0..1 (64-row half)
    const int wc   = w & 1;         // wave col 0..1
    const int quad = lane >> 4;     // 0..3
    const int lcol = lane & 15;     // 0..15

    f32x4 acc[4][4];
#pragma unroll
    for (int i = 0; i < 4; i++)
#pragma unroll
        for (int j = 0; j < 4; j++) {
            f32x4 z = {0.f, 0.f, 0.f, 0.f};
            acc[i][j] = z;
        }

    // per-lane base pointers: A rows (row0 + wr*64 + i*16 + lcol),
    //                         B rows (col0 + wc*64 + j*16 + lcol)
    const unsigned short* ap = xb + (size_t)(row0 + wr * 64 + lcol) * DIM + quad * 8;
    const unsigned short* bp = xb + (size_t)(col0 + wc * 64 + lcol) * DIM + quad * 8;

#pragma unroll
    for (int kk = 0; kk < 8; kk++) {
        bf16x8 a[4], b[4];
#pragma unroll
        for (int i = 0; i < 4; i++)
            a[i] = *(const bf16x8*)(ap + (size_t)(i * 16) * DIM + kk * 32);
#pragma unroll
        for (int j = 0; j < 4; j++)
            b[j] = *(const bf16x8*)(bp + (size_t)(j * 16) * DIM + kk * 32);
#pragma unroll
        for (int i = 0; i < 4; i++)
#pragma unroll
            for (int j = 0; j < 4; j++)
                acc[i][j] = __builtin_amdgcn_mfma_f32_16x16x32_bf16(a[i], b[j], acc[i][j], 0, 0, 0);
    }

    // epilogue: C/D layout col=lane&15, row=quad*4+reg
    float sc[4];
#pragma unroll
    for (int j = 0; j < 4; j++) sc[j] = sq[col0 + wc * 64 + j * 16 + lcol];

    float cs[4] = {0.f, 0.f, 0.f, 0.f};   // per-lane column partial sums

#pragma unroll
    for (int i = 0; i < 4; i++) {
        const int rbase = row0 + wr * 64 + i * 16 + quad * 4;
        const float4 s4 = *(const float4*)(sq + rbase);
        const float sr[4] = {s4.x, s4.y, s4.z, s4.w};
        float rs[4] = {0.f, 0.f, 0.f, 0.f};
#pragma unroll
        for (int j = 0; j < 4; j++) {
            const bool extile = diagblk && (wr * 4 + i == wc * 4 + j);
            float csj = 0.f;
#pragma unroll
            for (int r = 0; r < 4; r++) {
                float d2 = sr[r] + sc[j] - 2.f * acc[i][j][r];
                float dd = sqrtf(fmaxf(d2, 0.f));
                float e = __expf(dd - SHIFT);
                if (extile && (((quad * 4 + r) >> 3) == (lcol >> 3))) e = 0.f;
                rs[r] += e;
                csj += e;
            }
            cs[j] += csj;
        }
        // row sums: reduce across the 16 lanes of this quad
#pragma unroll
        for (int m = 1; m < 16; m <<= 1) {
#pragma unroll
            for (int r = 0; r < 4; r++) rs[r] += __shfl_xor(rs[r], m);
        }
        if (lcol == 0) {
#pragma unroll
            for (int r = 0; r < 4; r++) atomicAdd(&S[rbase + r], rs[r]);
        }
    }

    if (!diagblk) {
        // column sums: reduce across quads (stride 16, 32), lanes 0..15 hold cols
#pragma unroll
        for (int j = 0; j < 4; j++) {
            cs[j] += __shfl_xor(cs[j], 16);
            cs[j] += __shfl_xor(cs[j], 32);
        }
        if (lane < 16) {
#pragma unroll
            for (int j = 0; j < 4; j++)
                atomicAdd(&S[col0 + wc * 64 + j * 16 + lane], cs[j]);
        }
    }
}

// per 8-block: 28 within-block fp32 distances -> nll -> one atomic per block
__global__ __launch_bounds__(256) void pairs_kernel(const float* __restrict__ x,
                                                    const float* __restrict__ S,
                                                    float* __restrict__ out) {
    __shared__ float wsum[4];
    const int tid = threadIdx.x;
    const int p = tid >> 3;     // pair id 0..31 (28 used)
    const int g = tid & 7;      // lane within pair group
    const int base = blockIdx.x * FPC;

    float nll = 0.f;
    if (p < 28) {
        int a = 0, q = p;
        while (q >= 7 - a) { q -= 7 - a; a++; }
        const int b = a + 1 + q;                    // anchor=a, positive=b
        const float4* xa  = (const float4*)(x + (size_t)(base + a) * DIM);
        const float4* xbp = (const float4*)(x + (size_t)(base + b) * DIM);
        float d2 = 0.f;
#pragma unroll
        for (int r = 0; r < 8; r++) {
            float4 va = xa[r * 8 + g], vb = xbp[r * 8 + g];
            float dx = va.x - vb.x, dy = va.y - vb.y;
            float dz = va.z - vb.z, dw = va.w - vb.w;
            d2 = fmaf(dx, dx, d2); d2 = fmaf(dy, dy, d2);
            d2 = fmaf(dz, dz, d2); d2 = fmaf(dw, dw, d2);
        }
        d2 += __shfl_xor(d2, 1);
        d2 += __shfl_xor(d2, 2);
        d2 += __shfl_xor(d2, 4);
        if (g == 0) {
            float dd = sqrtf(fmaxf(d2, 0.f));
            nll = SHIFT + __logf(S[base + a] + __expf(dd - SHIFT)) - dd;
        }
    }
#pragma unroll
    for (int off = 1; off < 64; off <<= 1) nll += __shfl_xor(nll, off);
    if ((tid & 63) == 0) wsum[tid >> 6] = nll;
    __syncthreads();
    if (tid == 0)
        atomicAdd(out, (wsum[0] + wsum[1] + wsum[2] + wsum[3]) * (1.0f / (float)NPAIR));
}

extern "C" void kernel_launch(void* const* d_in, const int* in_sizes, int n_in,
                              void* d_out, int out_size, void* d_ws, size_t ws_size,
                              hipStream_t stream) {
    const float* x = (const float*)d_in[0];
    float* sq = (float*)d_ws;
    float* S  = sq + BATCH;
    unsigned short* xb = (unsigned short*)(S + BATCH);
    float* out = (float*)d_out;

    prep_kernel<<<BATCH * 64 / 256, 256, 0, stream>>>(x, sq, S, xb, out);

    dist_expsum_mfma<<<528, 256, 0, stream>>>(xb, sq, S);

    pairs_kernel<<<BATCH / FPC, 256, 0, stream>>>(x, S, out);
}

// Round 8
// 87.023 us; speedup vs baseline: 1.1595x; 1.1595x over previous
//
#include <hip/hip_runtime.h>
#include <math.h>

#define BATCH 4096
#define DIM 256
#define FPC 8
#define NPAIR 14336   // 512 blocks * C(8,2)
#define SHIFT 22.0f

typedef __bf16 bf16x8 __attribute__((ext_vector_type(8)));
typedef float  f32x4  __attribute__((ext_vector_type(4)));

// fp32 -> bf16 round-to-nearest-even (inputs are finite normals; no NaN path)
__device__ __forceinline__ unsigned short f2bf(float f) {
    unsigned int u = __float_as_uint(f);
    u += 0x7FFFu + ((u >> 16) & 1u);
    return (unsigned short)(u >> 16);
}

// async global->LDS, 16B per lane; dest = wave-uniform base + lane*16
__device__ __forceinline__ void g2l16(const void* g, void* l) {
    __builtin_amdgcn_global_load_lds((__attribute__((address_space(1))) void*)(g),
                                     (__attribute__((address_space(3))) void*)(l),
                                     16, 0, 0);
}

// ---------------------------------------------------------------------------
// ws layout (floats): [0,4096) sq ; [4096, 4096+4096*64) P partials ; then
// 4096*256 bf16 xb. P[r][k]: 64 conflict-free partial exp-sums per row --
// written exactly once each by construction (no zero-init, no atomics).
// ---------------------------------------------------------------------------

__global__ __launch_bounds__(256) void prep_kernel(const float* __restrict__ x,
                                                   float* __restrict__ sq,
                                                   unsigned short* __restrict__ xb,
                                                   float* __restrict__ out) {
    int t = blockIdx.x * 256 + threadIdx.x;
    int row = t >> 6;
    int lane = t & 63;
    float4 v = ((const float4*)(x + row * DIM))[lane];
    ushort4 b;
    b.x = f2bf(v.x); b.y = f2bf(v.y); b.z = f2bf(v.z); b.w = f2bf(v.w);
    ((ushort4*)(xb + row * DIM))[lane] = b;
    float s = v.x * v.x + v.y * v.y + v.z * v.z + v.w * v.w;
#pragma unroll
    for (int off = 32; off > 0; off >>= 1) s += __shfl_xor(s, off);
    if (lane == 0) sq[row] = s;
    if (t == 0) out[0] = 0.f;
}

// Upper-triangular 128x128 tile of dist = sqrt(sq_r - 2*X@X^T + sq_c).
// Row exp-sums (and, off-diagonal, column exp-sums by symmetry) are written as
// PLAIN STORES into conflict-free slots of P: tile(bi,bj) wave(wr,wc) writes
// row-partials to P[row][2*bj+wc], col-partials to P[col][2*bi+wr]. For any
// row in stripe s, col-parts occupy slots 0..2s-1 and row-parts 2s..63: all
// 64 slots written exactly once -- zero atomics, no init dependency.
__global__ __launch_bounds__(256) void dist_expsum_mfma(const unsigned short* __restrict__ xb,
                                                        const float* __restrict__ sq,
                                                        float* __restrict__ P) {
    __shared__ unsigned short As[128][128];   // 32KB: 128 rows x 256B (16 chunks)
    __shared__ unsigned short Bs[128][128];   // 32KB

    // triangular decode: tile (bi, bj) with bi <= bj
    int t = blockIdx.x, bi = 0;
    while (t >= 32 - bi) { t -= 32 - bi; bi++; }
    const int bj = bi + t;
    const int row0 = bi * 128;
    const int col0 = bj * 128;
    const bool diagblk = (bi == bj);

    const int tid  = threadIdx.x;
    const int w    = tid >> 6;      // wave 0..3
    const int lane = tid & 63;
    const int wr   = w >> 1;        // wave row 0..1 (64-row half)
    const int wc   = w & 1;         // wave col 0..1
    const int quad = lane >> 4;     // 0..3
    const int lcol = lane & 15;     // 0..15

    f32x4 acc[4][4];
#pragma unroll
    for (int i = 0; i < 4; i++)
#pragma unroll
        for (int j = 0; j < 4; j++) {
            f32x4 z = {0.f, 0.f, 0.f, 0.f};
            acc[i][j] = z;
        }

    // staging: one g2l16 = 4 rows x 256B; lane covers (row lane>>4, chunk lane&15)
    const int lrow = lane >> 4;     // 0..3
    const int lchk = lane & 15;     // linear LDS slot chunk

    for (int ph = 0; ph < 2; ph++) {
        const int k0 = ph * 128;
        __syncthreads();   // previous phase's reads done before overwrite
#pragma unroll
        for (int c = 0; c < 8; c++) {
            const int rb = w * 32 + c * 4;          // wave w stages rows [w*32, w*32+32)
            const int r  = rb + lrow;
            const int gc = (lchk ^ (r & 15)) * 8;   // swizzled global chunk (elems)
            g2l16(xb + (size_t)(row0 + r) * DIM + k0 + gc,
                  (unsigned short*)&As[rb][0] + lane * 8);
            g2l16(xb + (size_t)(col0 + r) * DIM + k0 + gc,
                  (unsigned short*)&Bs[rb][0] + lane * 8);
        }
        __syncthreads();   // single vmcnt drain for 16 outstanding loads/wave

#pragma unroll
        for (int kk = 0; kk < 4; kk++) {
            const int slot = (((kk * 4 + quad) ^ lcol)) * 8;
            bf16x8 a[4], b[4];
#pragma unroll
            for (int i = 0; i < 4; i++)
                a[i] = *(const bf16x8*)&As[wr * 64 + i * 16 + lcol][slot];
#pragma unroll
            for (int j = 0; j < 4; j++)
                b[j] = *(const bf16x8*)&Bs[wc * 64 + j * 16 + lcol][slot];
#pragma unroll
            for (int i = 0; i < 4; i++)
#pragma unroll
                for (int j = 0; j < 4; j++)
                    acc[i][j] = __builtin_amdgcn_mfma_f32_16x16x32_bf16(a[i], b[j], acc[i][j], 0, 0, 0);
        }
    }

    // epilogue: C/D layout col=lane&15, row=quad*4+reg
    float sc[4];
#pragma unroll
    for (int j = 0; j < 4; j++) sc[j] = sq[col0 + wc * 64 + j * 16 + lcol];

    float cs[4] = {0.f, 0.f, 0.f, 0.f};   // per-lane column partial sums

    const int rslot = 2 * bj + wc;        // this wave's row-partial slot
    const int cslot = 2 * bi + wr;        // this wave's col-partial slot

#pragma unroll
    for (int i = 0; i < 4; i++) {
        const int rbase = row0 + wr * 64 + i * 16 + quad * 4;
        const float4 s4 = *(const float4*)(sq + rbase);
        const float sr[4] = {s4.x, s4.y, s4.z, s4.w};
        float rs[4] = {0.f, 0.f, 0.f, 0.f};
#pragma unroll
        for (int j = 0; j < 4; j++) {
            const bool extile = diagblk && (wr * 4 + i == wc * 4 + j);
            float csj = 0.f;
#pragma unroll
            for (int r = 0; r < 4; r++) {
                float d2 = sr[r] + sc[j] - 2.f * acc[i][j][r];
                float dd = sqrtf(fmaxf(d2, 0.f));
                float e = __expf(dd - SHIFT);
                if (extile && (((quad * 4 + r) >> 3) == (lcol >> 3))) e = 0.f;
                rs[r] += e;
                csj += e;
            }
            cs[j] += csj;
        }
        // row sums: reduce across the 16 lanes of this quad
#pragma unroll
        for (int m = 1; m < 16; m <<= 1) {
#pragma unroll
            for (int r = 0; r < 4; r++) rs[r] += __shfl_xor(rs[r], m);
        }
        if (lcol == 0) {
#pragma unroll
            for (int r = 0; r < 4; r++) P[(size_t)(rbase + r) * 64 + rslot] = rs[r];
        }
    }

    if (!diagblk) {
        // column sums: reduce across quads (stride 16, 32), lanes 0..15 hold cols
#pragma unroll
        for (int j = 0; j < 4; j++) {
            cs[j] += __shfl_xor(cs[j], 16);
            cs[j] += __shfl_xor(cs[j], 32);
        }
        if (lane < 16) {
#pragma unroll
            for (int j = 0; j < 4; j++)
                P[(size_t)(col0 + wc * 64 + j * 16 + lane) * 64 + cslot] = cs[j];
        }
    }
}

// per 8-block: reduce P -> S for its 8 rows, then 28 within-block fp32
// distances -> nll -> one atomic per block
__global__ __launch_bounds__(256) void pairs_kernel(const float* __restrict__ x,
                                                    const float* __restrict__ P,
                                                    float* __restrict__ out) {
    __shared__ float Srow[FPC];
    __shared__ float wsum[4];
    const int tid = threadIdx.x;
    const int base = blockIdx.x * FPC;

    // S[base+rl] = sum_k P[base+rl][k]; 32 lanes x 2 coalesced loads per row
    {
        const int rl  = tid >> 5;    // 0..7
        const int l32 = tid & 31;
        const float* pr = P + (size_t)(base + rl) * 64;
        float s2 = pr[l32] + pr[32 + l32];
#pragma unroll
        for (int m = 1; m < 32; m <<= 1) s2 += __shfl_xor(s2, m);
        if (l32 == 0) Srow[rl] = s2;
    }
    __syncthreads();

    const int p = tid >> 3;     // pair id 0..31 (28 used)
    const int g = tid & 7;      // lane within pair group

    float nll = 0.f;
    if (p < 28) {
        int a = 0, q = p;
        while (q >= 7 - a) { q -= 7 - a; a++; }
        const int b = a + 1 + q;                    // anchor=a, positive=b
        const float4* xa  = (const float4*)(x + (size_t)(base + a) * DIM);
        const float4* xbp = (const float4*)(x + (size_t)(base + b) * DIM);
        float d2 = 0.f;
#pragma unroll
        for (int r = 0; r < 8; r++) {
            float4 va = xa[r * 8 + g], vb = xbp[r * 8 + g];
            float dx = va.x - vb.x, dy = va.y - vb.y;
            float dz = va.z - vb.z, dw = va.w - vb.w;
            d2 = fmaf(dx, dx, d2); d2 = fmaf(dy, dy, d2);
            d2 = fmaf(dz, dz, d2); d2 = fmaf(dw, dw, d2);
        }
        d2 += __shfl_xor(d2, 1);
        d2 += __shfl_xor(d2, 2);
        d2 += __shfl_xor(d2, 4);
        if (g == 0) {
            float dd = sqrtf(fmaxf(d2, 0.f));
            nll = SHIFT + __logf(Srow[a] + __expf(dd - SHIFT)) - dd;
        }
    }
#pragma unroll
    for (int off = 1; off < 64; off <<= 1) nll += __shfl_xor(nll, off);
    if ((tid & 63) == 0) wsum[tid >> 6] = nll;
    __syncthreads();
    if (tid == 0)
        atomicAdd(out, (wsum[0] + wsum[1] + wsum[2] + wsum[3]) * (1.0f / (float)NPAIR));
}

extern "C" void kernel_launch(void* const* d_in, const int* in_sizes, int n_in,
                              void* d_out, int out_size, void* d_ws, size_t ws_size,
                              hipStream_t stream) {
    const float* x = (const float*)d_in[0];
    float* sq = (float*)d_ws;
    float* P  = sq + BATCH;                          // [4096][64] f32, 1 MB
    unsigned short* xb = (unsigned short*)(P + (size_t)BATCH * 64);
    float* out = (float*)d_out;

    prep_kernel<<<BATCH * 64 / 256, 256, 0, stream>>>(x, sq, xb, out);

    dist_expsum_mfma<<<528, 256, 0, stream>>>(xb, sq, P);

    pairs_kernel<<<BATCH / FPC, 256, 0, stream>>>(x, P, out);
}

// Round 10
// 82.532 us; speedup vs baseline: 1.2225x; 1.0544x over previous
//
#include <hip/hip_runtime.h>
#include <math.h>

#define BATCH 4096
#define DIM 256
#define FPC 8
#define NPAIR 14336   // 512 blocks * C(8,2)
#define SHIFT 22.0f
#define NT 64         // 64 stripes of 64 rows
#define NTILE (NT * (NT + 1) / 2)   // 2080 upper-triangular 64x64 tiles

typedef __bf16 bf16x8 __attribute__((ext_vector_type(8)));
typedef float  f32x4  __attribute__((ext_vector_type(4)));

// fp32 -> bf16 round-to-nearest-even (inputs are finite normals; no NaN path)
__device__ __forceinline__ unsigned short f2bf(float f) {
    unsigned int u = __float_as_uint(f);
    u += 0x7FFFu + ((u >> 16) & 1u);
    return (unsigned short)(u >> 16);
}

// async global->LDS, 16B per lane; dest = wave-uniform base + lane*16
__device__ __forceinline__ void g2l16(const void* g, void* l) {
    __builtin_amdgcn_global_load_lds((__attribute__((address_space(1))) void*)(g),
                                     (__attribute__((address_space(3))) void*)(l),
                                     16, 0, 0);
}

// ---------------------------------------------------------------------------
// ws layout (floats): [0,4096) sq ; [4096, 4096+4096*128) P partials ; then
// xb bf16 (2 MB). P[r][k]: 128 conflict-free partial exp-sums per row, each
// written exactly once by construction (no zero-init, no atomics):
// row in stripe s gets col-partials in slots 0..2s-1, row-partials 2s..127.
// ---------------------------------------------------------------------------

__global__ __launch_bounds__(256) void prep_kernel(const float* __restrict__ x,
                                                   float* __restrict__ sq,
                                                   unsigned short* __restrict__ xb,
                                                   float* __restrict__ out) {
    int t = blockIdx.x * 256 + threadIdx.x;
    int row = t >> 6;
    int lane = t & 63;
    float4 v = ((const float4*)(x + row * DIM))[lane];
    ushort4 b;
    b.x = f2bf(v.x); b.y = f2bf(v.y); b.z = f2bf(v.z); b.w = f2bf(v.w);
    ((ushort4*)(xb + row * DIM))[lane] = b;
    float s = v.x * v.x + v.y * v.y + v.z * v.z + v.w * v.w;
#pragma unroll
    for (int off = 32; off > 0; off >>= 1) s += __shfl_xor(s, off);
    if (lane == 0) sq[row] = s;
    if (t == 0) out[0] = 0.f;
}

// 64x64 upper-triangular tile of dist = sqrt(sq_r - 2*X@X^T + sq_c).
// 256 threads = 2x2 waves of 32x32. Row exp-sums -> P[row][2*bj+wc]; for
// off-diagonal tiles also column exp-sums -> P[col][2*bi+wr] (symmetry).
// 16KB LDS -> 5+ blocks/CU; 2080 blocks -> real occupancy for latency hiding.
__global__ __launch_bounds__(256) void dist_expsum_mfma(const unsigned short* __restrict__ xb,
                                                        const float* __restrict__ sq,
                                                        float* __restrict__ P) {
    __shared__ unsigned short As[64][64];   // 8KB: 64 rows x 128B (8 chunks)
    __shared__ unsigned short Bs[64][64];   // 8KB

    // triangular decode: tile (bi, bj) with bi <= bj
    int t = blockIdx.x, bi = 0;
    while (t >= NT - bi) { t -= NT - bi; bi++; }
    const int bj = bi + t;
    const int row0 = bi * 64;
    const int col0 = bj * 64;
    const bool diagblk = (bi == bj);

    const int tid  = threadIdx.x;
    const int w    = tid >> 6;      // wave 0..3
    const int lane = tid & 63;
    const int wr   = w >> 1;        // wave row 0..1 (32-row half)
    const int wc   = w & 1;         // wave col 0..1
    const int quad = lane >> 4;     // 0..3
    const int lcol = lane & 15;     // 0..15

    f32x4 acc[2][2];
#pragma unroll
    for (int i = 0; i < 2; i++)
#pragma unroll
        for (int j = 0; j < 2; j++) {
            f32x4 z = {0.f, 0.f, 0.f, 0.f};
            acc[i][j] = z;
        }

    // staging: one g2l16 = 8 rows x 128B; lane -> (row lane>>3, chunk lane&7),
    // global chunk swizzled by row: (lane&7) ^ (lane>>3)
    const int swz = ((lane & 7) ^ (lane >> 3)) * 8;   // global elem offset
    const int ldsoff = lane * 8;                       // linear LDS dest (elems)

    for (int ph = 0; ph < 4; ph++) {
        const int k0 = ph * 64;
        __syncthreads();   // previous phase's reads done before overwrite
#pragma unroll
        for (int c = 0; c < 2; c++) {
            const int rb = w * 16 + c * 8;          // wave w stages rows [w*16, w*16+16)
            const int r  = rb + (lane >> 3);
            g2l16(xb + (size_t)(row0 + r) * DIM + k0 + swz,
                  (unsigned short*)&As[rb][0] + ldsoff);
            g2l16(xb + (size_t)(col0 + r) * DIM + k0 + swz,
                  (unsigned short*)&Bs[rb][0] + ldsoff);
        }
        __syncthreads();   // drain for 4 outstanding loads/wave

#pragma unroll
        for (int kk = 0; kk < 2; kk++) {
            const int slot = ((kk * 4 + quad) ^ (lcol & 7)) * 8;
            bf16x8 a[2], b[2];
#pragma unroll
            for (int i = 0; i < 2; i++)
                a[i] = *(const bf16x8*)&As[wr * 32 + i * 16 + lcol][slot];
#pragma unroll
            for (int j = 0; j < 2; j++)
                b[j] = *(const bf16x8*)&Bs[wc * 32 + j * 16 + lcol][slot];
#pragma unroll
            for (int i = 0; i < 2; i++)
#pragma unroll
                for (int j = 0; j < 2; j++)
                    acc[i][j] = __builtin_amdgcn_mfma_f32_16x16x32_bf16(a[i], b[j], acc[i][j], 0, 0, 0);
        }
    }

    // epilogue: C/D layout col=lane&15, row=quad*4+reg
    float sc2[2];
#pragma unroll
    for (int j = 0; j < 2; j++) sc2[j] = sq[col0 + wc * 32 + j * 16 + lcol];

    float cs[2] = {0.f, 0.f};             // per-lane column partial sums
    const int rslot = 2 * bj + wc;        // row-partial slot
    const int cslot = 2 * bi + wr;        // col-partial slot

#pragma unroll
    for (int i = 0; i < 2; i++) {
        const int rbase = row0 + wr * 32 + i * 16 + quad * 4;
        const float4 s4 = *(const float4*)(sq + rbase);
        const float sr[4] = {s4.x, s4.y, s4.z, s4.w};
        float rs[4] = {0.f, 0.f, 0.f, 0.f};
#pragma unroll
        for (int j = 0; j < 2; j++) {
            const bool extile = diagblk && (wr * 2 + i == wc * 2 + j);
            float csj = 0.f;
#pragma unroll
            for (int r = 0; r < 4; r++) {
                float d2 = sr[r] + sc2[j] - 2.f * acc[i][j][r];
                float dd = sqrtf(fmaxf(d2, 0.f));
                float e = __expf(dd - SHIFT);
                if (extile && (((quad * 4 + r) >> 3) == (lcol >> 3))) e = 0.f;
                rs[r] += e;
                csj += e;
            }
            cs[j] += csj;
        }
        // row sums: reduce across the 16 lanes of this quad
#pragma unroll
        for (int m = 1; m < 16; m <<= 1) {
#pragma unroll
            for (int r = 0; r < 4; r++) rs[r] += __shfl_xor(rs[r], m);
        }
        if (lcol == 0) {
#pragma unroll
            for (int r = 0; r < 4; r++) P[(size_t)(rbase + r) * 128 + rslot] = rs[r];
        }
    }

    if (!diagblk) {
        // column sums: reduce across quads (stride 16, 32), lanes 0..15 hold cols
#pragma unroll
        for (int j = 0; j < 2; j++) {
            cs[j] += __shfl_xor(cs[j], 16);
            cs[j] += __shfl_xor(cs[j], 32);
        }
        if (lane < 16) {
#pragma unroll
            for (int j = 0; j < 2; j++)
                P[(size_t)(col0 + wc * 32 + j * 16 + lane) * 128 + cslot] = cs[j];
        }
    }
}

// per 8-block: reduce P -> S for its 8 rows, then 28 within-block fp32
// distances -> nll -> one atomic per block
__global__ __launch_bounds__(256) void pairs_kernel(const float* __restrict__ x,
                                                    const float* __restrict__ P,
                                                    float* __restrict__ out) {
    __shared__ float Srow[FPC];
    __shared__ float wsum[4];
    const int tid = threadIdx.x;
    const int base = blockIdx.x * FPC;

    // S[base+rl] = sum_k P[base+rl][k]; 32 lanes x 4 coalesced loads per row
    {
        const int rl  = tid >> 5;    // 0..7
        const int l32 = tid & 31;
        const float* pr = P + (size_t)(base + rl) * 128;
        float s2 = (pr[l32] + pr[32 + l32]) + (pr[64 + l32] + pr[96 + l32]);
#pragma unroll
        for (int m = 1; m < 32; m <<= 1) s2 += __shfl_xor(s2, m);
        if (l32 == 0) Srow[rl] = s2;
    }
    __syncthreads();

    const int p = tid >> 3;     // pair id 0..31 (28 used)
    const int g = tid & 7;      // lane within pair group

    float nll = 0.f;
    if (p < 28) {
        int a = 0, q = p;
        while (q >= 7 - a) { q -= 7 - a; a++; }
        const int b = a + 1 + q;                    // anchor=a, positive=b
        const float4* xa  = (const float4*)(x + (size_t)(base + a) * DIM);
        const float4* xbp = (const float4*)(x + (size_t)(base + b) * DIM);
        float d2 = 0.f;
#pragma unroll
        for (int r = 0; r < 8; r++) {
            float4 va = xa[r * 8 + g], vb = xbp[r * 8 + g];
            float dx = va.x - vb.x, dy = va.y - vb.y;
            float dz = va.z - vb.z, dw = va.w - vb.w;
            d2 = fmaf(dx, dx, d2); d2 = fmaf(dy, dy, d2);
            d2 = fmaf(dz, dz, d2); d2 = fmaf(dw, dw, d2);
        }
        d2 += __shfl_xor(d2, 1);
        d2 += __shfl_xor(d2, 2);
        d2 += __shfl_xor(d2, 4);
        if (g == 0) {
            float dd = sqrtf(fmaxf(d2, 0.f));
            nll = SHIFT + __logf(Srow[a] + __expf(dd - SHIFT)) - dd;
        }
    }
#pragma unroll
    for (int off = 1; off < 64; off <<= 1) nll += __shfl_xor(nll, off);
    if ((tid & 63) == 0) wsum[tid >> 6] = nll;
    __syncthreads();
    if (tid == 0)
        atomicAdd(out, (wsum[0] + wsum[1] + wsum[2] + wsum[3]) * (1.0f / (float)NPAIR));
}

extern "C" void kernel_launch(void* const* d_in, const int* in_sizes, int n_in,
                              void* d_out, int out_size, void* d_ws, size_t ws_size,
                              hipStream_t stream) {
    const float* x = (const float*)d_in[0];
    float* sq = (float*)d_ws;
    float* P  = sq + BATCH;                          // [4096][128] f32, 2 MB
    unsigned short* xb = (unsigned short*)(P + (size_t)BATCH * 128);
    float* out = (float*)d_out;

    prep_kernel<<<BATCH * 64 / 256, 256, 0, stream>>>(x, sq, xb, out);

    dist_expsum_mfma<<<NTILE, 256, 0, stream>>>(xb, sq, P);

    pairs_kernel<<<BATCH / FPC, 256, 0, stream>>>(x, P, out);
}